// Round 2
// baseline (285.532 us; speedup 1.0000x reference)
//
#include <hip/hip_runtime.h>
#include <math.h>
#include <float.h>

#define KSEL 30
#define KNRM 8
#define CAP  512
#define G    32
#define NCELL (G*G*G)
#define GLO  (-4.8f)
#define Hc   (0.3f)
#define INVH (3.3333333333f)

__device__ __forceinline__ int cell_coord(float x) {
    int c = (int)floorf((x - GLO) * INVH);
    return c < 0 ? 0 : (c > G - 1 ? G - 1 : c);
}

// ---------------- Kernel: precompute B (6x6) and q (6) into ws[0..41] ----------------
// scores[k,l]*sqrt(D) = r_k^T B r_l + (terms const in l, cancel in softmax) + q . r_l
__global__ __launch_bounds__(256) void k_precompute(
    const float* __restrict__ fc_w, const float* __restrict__ fc_b,
    const float* __restrict__ wq_w, const float* __restrict__ wq_b,
    const float* __restrict__ wk_w, const float* __restrict__ wk_b,
    float* __restrict__ ws)
{
    __shared__ float Gq[128][6];
    __shared__ float Gk[128][6];
    __shared__ float hq[128];
    const int tid = threadIdx.x;

    for (int e = tid; e < 768; e += 256) {
        int r = e / 6, c = e % 6;
        float aq = 0.f, ak = 0.f;
        for (int m = 0; m < 128; ++m) {
            float f = fc_w[m * 6 + c];
            aq += wq_w[r * 128 + m] * f;
            ak += wk_w[r * 128 + m] * f;
        }
        Gq[r][c] = aq;
        Gk[r][c] = ak;
    }
    if (tid < 128) {
        float a = wq_b[tid];
        for (int m = 0; m < 128; ++m) a += wq_w[tid * 128 + m] * fc_b[m];
        hq[tid] = a;
    }
    __syncthreads();

    const float inv_s = 0.0883883476483184f; // 1/sqrt(128)
    if (tid < 36) {
        int a = tid / 6, b = tid % 6;
        float s = 0.f;
        for (int i = 0; i < 128; ++i) s += Gq[i][a] * Gk[i][b];
        ws[tid] = s * inv_s;                 // B row-major: ws[a*6+b]
    }
    if (tid >= 64 && tid < 70) {
        int b = tid - 64;
        float s = 0.f;
        for (int i = 0; i < 128; ++i) s += Gk[i][b] * hq[i];
        ws[36 + b] = s * inv_s;              // q
    }
}

// ---------------- Grid build ----------------
__global__ __launch_bounds__(256) void k_hist(
    const float* __restrict__ vp, int* __restrict__ cell_cnt, int M)
{
    int i = blockIdx.x * 256 + threadIdx.x;
    if (i < M) {
        int cx = cell_coord(vp[i * 3 + 0]);
        int cy = cell_coord(vp[i * 3 + 1]);
        int cz = cell_coord(vp[i * 3 + 2]);
        atomicAdd(&cell_cnt[(cx * G + cy) * G + cz], 1);
    }
}

// single block: exclusive-scan 32768 counts -> cell_end initialized to exclusive start
__global__ __launch_bounds__(256) void k_scan(
    const int* __restrict__ cell_cnt, int* __restrict__ cell_end)
{
    __shared__ int part[256];
    const int tid = threadIdx.x;
    const int base = tid * (NCELL / 256);
    int s = 0;
    for (int k = 0; k < NCELL / 256; ++k) s += cell_cnt[base + k];
    part[tid] = s;
    __syncthreads();
    for (int off = 1; off < 256; off <<= 1) {
        int v = (tid >= off) ? part[tid - off] : 0;
        __syncthreads();
        part[tid] += v;
        __syncthreads();
    }
    int run = part[tid] - s; // exclusive start of this chunk
    for (int k = 0; k < NCELL / 256; ++k) {
        cell_end[base + k] = run;
        run += cell_cnt[base + k];
    }
}

// scatter: after this, cell_end[c] = start + count (end); range = [end-cnt, end)
__global__ __launch_bounds__(256) void k_scatter(
    const float* __restrict__ vp, int* __restrict__ cell_end,
    float* __restrict__ spx, float* __restrict__ spy, float* __restrict__ spz,
    int* __restrict__ sidx, int M)
{
    int i = blockIdx.x * 256 + threadIdx.x;
    if (i < M) {
        float x = vp[i * 3 + 0], y = vp[i * 3 + 1], z = vp[i * 3 + 2];
        int c = (cell_coord(x) * G + cell_coord(y)) * G + cell_coord(z);
        int p = atomicAdd(&cell_end[c], 1);
        spx[p] = x; spy[p] = y; spz[p] = z; sidx[p] = i;
    }
}

__device__ __forceinline__ float gap1(float x, int i) {
    float lo = (i == 0)     ? -1e30f : GLO + (float)i * Hc;
    float hi = (i == G - 1) ?  1e30f : GLO + (float)(i + 1) * Hc;
    float g = 0.f;
    g = fmaxf(g, lo - x);
    g = fmaxf(g, x - hi);
    return g;
}

// ---------------- Main: per-point grid-kNN + reduced attention ----------------
__global__ __launch_bounds__(256) void k_main(
    const float* __restrict__ xw, const float* __restrict__ vp,
    const float* __restrict__ vn, const float* __restrict__ vv,
    const float* __restrict__ ws,
    const int* __restrict__ cell_cnt, const int* __restrict__ cell_end,
    const float* __restrict__ spx, const float* __restrict__ spy,
    const float* __restrict__ spz, const int* __restrict__ sidx,
    float* __restrict__ out, int M)
{
    const int n   = blockIdx.x;
    const int tid = threadIdx.x;

    __shared__ int                s_cnt;
    __shared__ unsigned long long s_key[CAP];
    __shared__ int                s_sel[KSEL];
    __shared__ float              s_vn[KSEL][3];
    __shared__ float              s_v[KSEL];
    __shared__ float              s_t[KSEL][6];
    __shared__ float              s_e[KSEL];
    __shared__ float              s_o[KSEL];
    __shared__ float              s_xn[3];

    const float x0 = xw[n * 3 + 0];
    const float x1 = xw[n * 3 + 1];
    const float x2 = xw[n * 3 + 2];

    const int cx = cell_coord(x0);
    const int cy = cell_coord(x1);
    const int cz = cell_coord(x2);

    auto midf = [](float a, float b) -> float {
        unsigned ua = __float_as_uint(a), ub = __float_as_uint(b);
        return __uint_as_float((ua + ub) >> 1);
    };

    // analytic radius: expected ~40 neighbors inside sqrt(T)
    float xn2 = x0 * x0 + x1 * x1 + x2 * x2;
    float rho = (float)M * 0.063493636f * __expf(-0.5f * xn2);
    float rc  = 30.0f / (rho * 4.1887902f);           // r30^3
    float T   = 1.3f * __powf(rc, 0.66666667f);       // squared-dist threshold

    float Tlo = 0.f, Thi = 0.f;
    bool  haveHi = false;
    int   nc = 0;

    for (int attempt = 0; attempt < 12; ++attempt) {
        if (tid == 0) s_cnt = 0;
        __syncthreads();

        float sq = sqrtf(T);
        int smax = (int)(sq * INVH) + 2;
        if (smax > G - 1) smax = G - 1;
        int ax0 = max(cx - smax, 0), ax1 = min(cx + smax, G - 1);
        int ay0 = max(cy - smax, 0), ay1 = min(cy + smax, G - 1);
        int az0 = max(cz - smax, 0), az1 = min(cz + smax, G - 1);
        int nx = ax1 - ax0 + 1, ny = ay1 - ay0 + 1, nz = az1 - az0 + 1;
        int tot = nx * ny * nz;
        float Tm = T * 1.000002f;

        for (int ci = tid; ci < tot; ci += 256) {
            int iz = ci % nz;
            int t2 = ci / nz;
            int iy = t2 % ny;
            int ix = t2 / ny;
            ix += ax0; iy += ay0; iz += az0;
            float gx = gap1(x0, ix), gy = gap1(x1, iy), gz = gap1(x2, iz);
            float mind2 = gx * gx + gy * gy + gz * gz;
            if (mind2 <= Tm) {
                int c = (ix * G + iy) * G + iz;
                int e = cell_end[c];
                int cnt = cell_cnt[c];
                for (int p = e - cnt; p < e; ++p) {
                    float dx = __fsub_rn(x0, spx[p]);
                    float dy = __fsub_rn(x1, spy[p]);
                    float dz = __fsub_rn(x2, spz[p]);
                    float d2 = __fadd_rn(__fadd_rn(__fmul_rn(dx, dx), __fmul_rn(dy, dy)),
                                         __fmul_rn(dz, dz));
                    if (d2 < T) {
                        int pos = atomicAdd(&s_cnt, 1);
                        if (pos < CAP) {
                            s_key[pos] = ((unsigned long long)__float_as_uint(d2) << 32) |
                                         (unsigned)sidx[p];
                        }
                    }
                }
            }
        }
        __syncthreads();
        nc = s_cnt;
        if (nc >= KSEL && nc <= CAP) break;
        if (nc < KSEL) { Tlo = T; T = haveHi ? midf(Tlo, Thi) : T * 3.0f; }
        else           { Thi = T; haveHi = true; T = midf(Tlo, Thi); }
        __syncthreads();
    }
    if (nc > CAP) nc = CAP; // safety (should be unreachable)

    if (tid < KSEL) s_sel[tid] = 0; // safety init
    __syncthreads();

    // exact top-30 by rank (keys distinct => unique ranks; idx tiebreak = lax.top_k)
    for (int i0 = tid; i0 < nc; i0 += 256) {
        unsigned long long me = s_key[i0];
        int rank = 0;
        for (int i = 0; i < nc; ++i) rank += (s_key[i] < me) ? 1 : 0;
        if (rank < KSEL) s_sel[rank] = (int)(me & 0xffffffffull);
    }
    __syncthreads();

    // ---- gather features ----
    float r0 = 0.f, r1 = 0.f, r2 = 0.f, r3 = 0.f, r4 = 0.f, r5 = 0.f;
    if (tid < KSEL) {
        int ix = s_sel[tid];
        r0 = __fsub_rn(x0, vp[ix * 3 + 0]);
        r1 = __fsub_rn(x1, vp[ix * 3 + 1]);
        r2 = __fsub_rn(x2, vp[ix * 3 + 2]);
        s_vn[tid][0] = vn[ix * 3 + 0];
        s_vn[tid][1] = vn[ix * 3 + 1];
        s_vn[tid][2] = vn[ix * 3 + 2];
        s_v[tid]     = vv[ix];
    }
    __syncthreads();
    if (tid == 0) {
        float a0 = 0.f, a1 = 0.f, a2 = 0.f;
        for (int k = 0; k < KNRM; ++k) {
            a0 += s_vn[k][0]; a1 += s_vn[k][1]; a2 += s_vn[k][2];
        }
        s_xn[0] = a0 * 0.125f; s_xn[1] = a1 * 0.125f; s_xn[2] = a2 * 0.125f;
    }
    __syncthreads();

    if (tid < KSEL) {
        r3 = __fsub_rn(s_xn[0], s_vn[tid][0]);
        r4 = __fsub_rn(s_xn[1], s_vn[tid][1]);
        r5 = __fsub_rn(s_xn[2], s_vn[tid][2]);
        float rr[6] = {r0, r1, r2, r3, r4, r5};
        float e = 0.f;
#pragma unroll
        for (int i = 0; i < 6; ++i) e += ws[36 + i] * rr[i];
        s_e[tid] = e;
#pragma unroll
        for (int j = 0; j < 6; ++j) {
            float t = 0.f;
#pragma unroll
            for (int i = 0; i < 6; ++i) t += ws[j * 6 + i] * rr[i];
            s_t[tid][j] = t;
        }
    }
    __syncthreads();

    if (tid < KSEL) {
        float sc[KSEL];
        float mx = -1e30f;
#pragma unroll
        for (int l = 0; l < KSEL; ++l) {
            float s = s_e[l];
            s += r0 * s_t[l][0];
            s += r1 * s_t[l][1];
            s += r2 * s_t[l][2];
            s += r3 * s_t[l][3];
            s += r4 * s_t[l][4];
            s += r5 * s_t[l][5];
            sc[l] = s;
            mx = fmaxf(mx, s);
        }
        float den = 0.f, num = 0.f;
#pragma unroll
        for (int l = 0; l < KSEL; ++l) {
            float w = __expf(sc[l] - mx);
            den += w;
            num += w * s_v[l];
        }
        s_o[tid] = num / den;
    }
    __syncthreads();

    if (tid == 0) {
        float a = 0.f;
        for (int k = 0; k < KSEL; ++k) a += s_o[k];
        out[n] = a * (1.0f / 30.0f);
    }
}

extern "C" void kernel_launch(void* const* d_in, const int* in_sizes, int n_in,
                              void* d_out, int out_size, void* d_ws, size_t ws_size,
                              hipStream_t stream)
{
    const float* xw   = (const float*)d_in[0];
    const float* vp   = (const float*)d_in[1];
    const float* vn   = (const float*)d_in[2];
    const float* vv   = (const float*)d_in[3];
    const float* fc_w = (const float*)d_in[4];
    const float* fc_b = (const float*)d_in[5];
    const float* wq_w = (const float*)d_in[6];
    const float* wq_b = (const float*)d_in[7];
    const float* wk_w = (const float*)d_in[8];
    const float* wk_b = (const float*)d_in[9];

    int N = in_sizes[0] / 3;
    int M = in_sizes[1] / 3;

    float* ws_f     = (float*)d_ws;
    int*   cell_cnt = (int*)(ws_f + 64);
    int*   cell_end = cell_cnt + NCELL;
    float* spx      = (float*)(cell_end + NCELL);
    float* spy      = spx + M;
    float* spz      = spy + M;
    int*   sidx     = (int*)(spz + M);

    hipMemsetAsync(cell_cnt, 0, NCELL * sizeof(int), stream);

    k_precompute<<<1, 256, 0, stream>>>(fc_w, fc_b, wq_w, wq_b, wk_w, wk_b, ws_f);
    k_hist<<<(M + 255) / 256, 256, 0, stream>>>(vp, cell_cnt, M);
    k_scan<<<1, 256, 0, stream>>>(cell_cnt, cell_end);
    k_scatter<<<(M + 255) / 256, 256, 0, stream>>>(vp, cell_end, spx, spy, spz, sidx, M);
    k_main<<<N, 256, 0, stream>>>(xw, vp, vn, vv, ws_f, cell_cnt, cell_end,
                                  spx, spy, spz, sidx, (float*)d_out, M);
}

// Round 5
// 130.979 us; speedup vs baseline: 2.1800x; 2.1800x over previous
//
#include <hip/hip_runtime.h>
#include <math.h>
#include <float.h>

#define KSEL 30
#define KNRM 8
#define CAP  512
#define G    32
#define NCELL (G*G*G)
#define GLO  (-4.8f)
#define Hc   (0.3f)
#define INVH (3.3333333333f)

typedef unsigned long long ull;

__device__ __forceinline__ int cell_coord(float x) {
    int c = (int)floorf((x - GLO) * INVH);
    return c < 0 ? 0 : (c > G - 1 ? G - 1 : c);
}

__device__ __forceinline__ float gap1(float x, int i) {
    float lo = (i == 0)     ? -1e30f : GLO + (float)i * Hc;
    float hi = (i == G - 1) ?  1e30f : GLO + (float)(i + 1) * Hc;
    float g = 0.f;
    g = fmaxf(g, lo - x);
    g = fmaxf(g, x - hi);
    return g;
}

// ---------------- precompute B (6x6) and q (6) into ws[0..41] ----------------
// scores[k,l]*sqrt(D) = r_k^T B r_l + (l-const terms, cancel in softmax) + q . r_l
__global__ __launch_bounds__(256) void k_precompute(
    const float* __restrict__ fc_w, const float* __restrict__ fc_b,
    const float* __restrict__ wq_w, const float* __restrict__ wq_b,
    const float* __restrict__ wk_w, const float* __restrict__ wk_b,
    float* __restrict__ ws)
{
    __shared__ float Gq[128][6];
    __shared__ float Gk[128][6];
    __shared__ float hq[128];
    const int tid = threadIdx.x;

    for (int e = tid; e < 768; e += 256) {
        int r = e / 6, c = e % 6;
        float aq = 0.f, ak = 0.f;
        for (int m = 0; m < 128; ++m) {
            float f = fc_w[m * 6 + c];
            aq += wq_w[r * 128 + m] * f;
            ak += wk_w[r * 128 + m] * f;
        }
        Gq[r][c] = aq;
        Gk[r][c] = ak;
    }
    if (tid < 128) {
        float a = wq_b[tid];
        for (int m = 0; m < 128; ++m) a += wq_w[tid * 128 + m] * fc_b[m];
        hq[tid] = a;
    }
    __syncthreads();

    const float inv_s = 0.0883883476483184f; // 1/sqrt(128)
    if (tid < 36) {
        int a = tid / 6, b = tid % 6;
        float s = 0.f;
        for (int i = 0; i < 128; ++i) s += Gq[i][a] * Gk[i][b];
        ws[tid] = s * inv_s;
    }
    if (tid >= 64 && tid < 70) {
        int b = tid - 64;
        float s = 0.f;
        for (int i = 0; i < 128; ++i) s += Gk[i][b] * hq[i];
        ws[36 + b] = s * inv_s;
    }
}

// ---------------- grid build ----------------
__global__ __launch_bounds__(256) void k_hist(
    const float* __restrict__ vp, int* __restrict__ cell_cnt, int M)
{
    int i = blockIdx.x * 256 + threadIdx.x;
    if (i < M) {
        int cx = cell_coord(vp[i * 3 + 0]);
        int cy = cell_coord(vp[i * 3 + 1]);
        int cz = cell_coord(vp[i * 3 + 2]);
        atomicAdd(&cell_cnt[(cx * G + cy) * G + cz], 1);
    }
}

// proven round-2 version (256 threads)
__global__ __launch_bounds__(256) void k_scan(
    const int* __restrict__ cell_cnt, int* __restrict__ cell_end)
{
    __shared__ int part[256];
    const int tid = threadIdx.x;
    const int base = tid * (NCELL / 256);
    int s = 0;
    for (int k = 0; k < NCELL / 256; ++k) s += cell_cnt[base + k];
    part[tid] = s;
    __syncthreads();
    for (int off = 1; off < 256; off <<= 1) {
        int v = (tid >= off) ? part[tid - off] : 0;
        __syncthreads();
        part[tid] += v;
        __syncthreads();
    }
    int run = part[tid] - s;
    for (int k = 0; k < NCELL / 256; ++k) {
        cell_end[base + k] = run;
        run += cell_cnt[base + k];
    }
}

// after this, cell_end[c] = end; range = [end-cnt, end).
__global__ __launch_bounds__(256) void k_scatter(
    const float* __restrict__ vp, int* __restrict__ cell_end,
    float4* __restrict__ sp4, int* __restrict__ sidx, int M)
{
    int i = blockIdx.x * 256 + threadIdx.x;
    if (i < M) {
        float x = vp[i * 3 + 0], y = vp[i * 3 + 1], z = vp[i * 3 + 2];
        int c = (cell_coord(x) * G + cell_coord(y)) * G + cell_coord(z);
        int p = atomicAdd(&cell_end[c], 1);
        sp4[p] = make_float4(x, y, z, 0.0f);
        sidx[p] = i;
    }
}

// ---------------- main: ONE WAVE (64 threads) per point, round-2 logic ----------------
__global__ __launch_bounds__(64) void k_main(
    const float* __restrict__ xw, const float* __restrict__ vp,
    const float* __restrict__ vn, const float* __restrict__ vv,
    const float* __restrict__ ws,
    const int* __restrict__ cc, const int* __restrict__ ce,
    const float4* __restrict__ sp4, const int* __restrict__ sidx,
    float* __restrict__ out, int M)
{
    const int n    = blockIdx.x;
    const int lane = threadIdx.x;

    __shared__ ull   s_key[CAP];
    __shared__ int   s_sel[KSEL];
    __shared__ float s_vn[KSEL][3];
    __shared__ float s_v[KSEL];
    __shared__ float s_t[KSEL][6];
    __shared__ float s_e[KSEL];
    __shared__ float s_o[KSEL];
    __shared__ float s_xn[3];
    __shared__ int   s_cnt;

    const float x0 = xw[n * 3 + 0];
    const float x1 = xw[n * 3 + 1];
    const float x2 = xw[n * 3 + 2];

    const int cx = cell_coord(x0);
    const int cy = cell_coord(x1);
    const int cz = cell_coord(x2);

    auto midf = [](float a, float b) -> float {
        unsigned ua = __float_as_uint(a), ub = __float_as_uint(b);
        return __uint_as_float((ua + ub) >> 1);
    };

    // damped fixed-point initial radius (undershoot-biased; starting guess only,
    // cannot affect the selected set — the bracketed search below is exact)
    const float c0 = 0.063493636f * (float)M * 4.18879020f;
    float R = sqrtf(x0 * x0 + x1 * x1 + x2 * x2);
    float r = cbrtf(30.0f / (c0 * __expf(-0.5f * R * R)));
#pragma unroll
    for (int it = 0; it < 4; ++it) {
        float d  = fmaxf(R - r, 0.0f);
        float rn = cbrtf(30.0f / (c0 * __expf(-0.5f * d * d)));
        r = sqrtf(r * rn);
    }
    float T = 1.2f * r * r;

    float Tlo = 0.f, Thi = 0.f;
    bool  haveHi = false, last = false;
    int   nc = 0;

    for (int attempt = 0; attempt < 24; ++attempt) {
        if (lane == 0) s_cnt = 0;
        __syncthreads();

        float Tm = T * 1.000002f;
        float sq = sqrtf(T);
        int smax = (int)(sq * INVH) + 2;
        if (smax > G - 1) smax = G - 1;
        int ax0 = max(cx - smax, 0), ax1 = min(cx + smax, G - 1);
        int ay0 = max(cy - smax, 0), ay1 = min(cy + smax, G - 1);
        int az0 = max(cz - smax, 0), az1 = min(cz + smax, G - 1);
        int nx = ax1 - ax0 + 1, nyv = ay1 - ay0 + 1, nz = az1 - az0 + 1;
        int tot = nx * nyv * nz;

        for (int ci = lane; ci < tot; ci += 64) {
            int iz = ci % nz;
            int t2 = ci / nz;
            int iy = t2 % nyv;
            int ix = t2 / nyv;
            ix += ax0; iy += ay0; iz += az0;
            float gx = gap1(x0, ix), gy = gap1(x1, iy), gz = gap1(x2, iz);
            float mind2 = gx * gx + gy * gy + gz * gz;
            if (mind2 <= Tm) {
                int c = (ix * G + iy) * G + iz;
                int e   = ce[c];
                int cnt = cc[c];
                for (int p = e - cnt; p < e; ++p) {
                    float4 q = sp4[p];
                    float dx = __fsub_rn(x0, q.x);
                    float dy = __fsub_rn(x1, q.y);
                    float dz = __fsub_rn(x2, q.z);
                    float d2 = __fadd_rn(__fadd_rn(__fmul_rn(dx, dx), __fmul_rn(dy, dy)),
                                         __fmul_rn(dz, dz));
                    if (d2 < T) {
                        int pos = atomicAdd(&s_cnt, 1);
                        if (pos < CAP) {
                            s_key[pos] = ((ull)__float_as_uint(d2) << 32) |
                                         (unsigned)sidx[p];
                        }
                    }
                }
            }
        }
        __syncthreads();
        nc = s_cnt;
        if (last || (nc >= KSEL && nc <= CAP)) break;
        if (nc < KSEL) { Tlo = T; T = haveHi ? midf(Tlo, Thi) : T * 2.5f; }
        else           { Thi = T; haveHi = true; T = midf(Tlo, Thi); }
        if (haveHi && (__float_as_uint(Thi) - __float_as_uint(Tlo) <= 1u)) {
            T = Thi;        // final guaranteed-superset pass
            last = true;
        }
        __syncthreads();
    }
    if (nc > CAP) nc = CAP;

    if (lane < KSEL) s_sel[lane] = 0; // safety init
    __syncthreads();

    // exact top-30 by rank (distinct keys; idx tiebreak = lax.top_k)
    for (int i0 = lane; i0 < nc; i0 += 64) {
        ull me = s_key[i0];
        int rank = 0;
        for (int i = 0; i < nc; ++i) rank += (s_key[i] < me) ? 1 : 0;
        if (rank < KSEL) s_sel[rank] = (int)(me & 0xffffffffull);
    }
    __syncthreads();

    // ---- gather features (round-2 verbatim) ----
    float r0 = 0.f, r1 = 0.f, r2 = 0.f;
    if (lane < KSEL) {
        int ix = s_sel[lane];
        r0 = __fsub_rn(x0, vp[ix * 3 + 0]);
        r1 = __fsub_rn(x1, vp[ix * 3 + 1]);
        r2 = __fsub_rn(x2, vp[ix * 3 + 2]);
        s_vn[lane][0] = vn[ix * 3 + 0];
        s_vn[lane][1] = vn[ix * 3 + 1];
        s_vn[lane][2] = vn[ix * 3 + 2];
        s_v[lane]     = vv[ix];
    }
    __syncthreads();
    if (lane == 0) {
        float a0 = 0.f, a1 = 0.f, a2 = 0.f;
        for (int k = 0; k < KNRM; ++k) {
            a0 += s_vn[k][0]; a1 += s_vn[k][1]; a2 += s_vn[k][2];
        }
        s_xn[0] = a0 * 0.125f; s_xn[1] = a1 * 0.125f; s_xn[2] = a2 * 0.125f;
    }
    __syncthreads();

    float r3 = 0.f, r4 = 0.f, r5 = 0.f;
    if (lane < KSEL) {
        r3 = __fsub_rn(s_xn[0], s_vn[lane][0]);
        r4 = __fsub_rn(s_xn[1], s_vn[lane][1]);
        r5 = __fsub_rn(s_xn[2], s_vn[lane][2]);
        float rr[6] = {r0, r1, r2, r3, r4, r5};
        float e = 0.f;
#pragma unroll
        for (int i = 0; i < 6; ++i) e += ws[36 + i] * rr[i];
        s_e[lane] = e;
#pragma unroll
        for (int j = 0; j < 6; ++j) {
            float t = 0.f;
#pragma unroll
            for (int i = 0; i < 6; ++i) t += ws[j * 6 + i] * rr[i];
            s_t[lane][j] = t;
        }
    }
    __syncthreads();

    if (lane < KSEL) {
        float sc[KSEL];
        float mx = -1e30f;
#pragma unroll
        for (int l = 0; l < KSEL; ++l) {
            float s = s_e[l];
            s += r0 * s_t[l][0];
            s += r1 * s_t[l][1];
            s += r2 * s_t[l][2];
            s += r3 * s_t[l][3];
            s += r4 * s_t[l][4];
            s += r5 * s_t[l][5];
            sc[l] = s;
            mx = fmaxf(mx, s);
        }
        float den = 0.f, num = 0.f;
#pragma unroll
        for (int l = 0; l < KSEL; ++l) {
            float w = __expf(sc[l] - mx);
            den += w;
            num += w * s_v[l];
        }
        s_o[lane] = num / den;
    }
    __syncthreads();

    if (lane == 0) {
        float a = 0.f;
        for (int k = 0; k < KSEL; ++k) a += s_o[k];
        out[n] = a * (1.0f / 30.0f);
    }
}

extern "C" void kernel_launch(void* const* d_in, const int* in_sizes, int n_in,
                              void* d_out, int out_size, void* d_ws, size_t ws_size,
                              hipStream_t stream)
{
    const float* xw   = (const float*)d_in[0];
    const float* vp   = (const float*)d_in[1];
    const float* vn   = (const float*)d_in[2];
    const float* vv   = (const float*)d_in[3];
    const float* fc_w = (const float*)d_in[4];
    const float* fc_b = (const float*)d_in[5];
    const float* wq_w = (const float*)d_in[6];
    const float* wq_b = (const float*)d_in[7];
    const float* wk_w = (const float*)d_in[8];
    const float* wk_b = (const float*)d_in[9];

    int N = in_sizes[0] / 3;
    int M = in_sizes[1] / 3;

    float*  ws_f = (float*)d_ws;
    int*    cc   = (int*)(ws_f + 64);
    int*    ce   = cc + NCELL;
    float4* sp4  = (float4*)(ce + NCELL);    // byte offset 262400, 16B-aligned
    int*    sidx = (int*)(sp4 + M);

    hipMemsetAsync(cc, 0, NCELL * sizeof(int), stream);

    k_precompute<<<1, 256, 0, stream>>>(fc_w, fc_b, wq_w, wq_b, wk_w, wk_b, ws_f);
    k_hist<<<(M + 255) / 256, 256, 0, stream>>>(vp, cc, M);
    k_scan<<<1, 256, 0, stream>>>(cc, ce);
    k_scatter<<<(M + 255) / 256, 256, 0, stream>>>(vp, ce, sp4, sidx, M);
    k_main<<<N, 64, 0, stream>>>(xw, vp, vn, vv, ws_f, cc, ce, sp4, sidx,
                                 (float*)d_out, M);
}

// Round 6
// 109.181 us; speedup vs baseline: 2.6152x; 1.1996x over previous
//
#include <hip/hip_runtime.h>
#include <math.h>
#include <float.h>

#define KSEL 30
#define KNRM 8
#define CAP  320
#define G    32
#define NCELL (G*G*G)
#define GLO  (-4.8f)
#define Hc   (0.3f)
#define INVH (3.3333333333f)
#define NWAVE 4

typedef unsigned long long ull;

__device__ __forceinline__ int cell_coord(float x) {
    int c = (int)floorf((x - GLO) * INVH);
    return c < 0 ? 0 : (c > G - 1 ? G - 1 : c);
}

__device__ __forceinline__ float gap1(float x, int i) {
    float lo = (i == 0)     ? -1e30f : GLO + (float)i * Hc;
    float hi = (i == G - 1) ?  1e30f : GLO + (float)(i + 1) * Hc;
    float g = 0.f;
    g = fmaxf(g, lo - x);
    g = fmaxf(g, x - hi);
    return g;
}

// ---- hist (blocks 0..nHist-1) + precompute of B/q (block nHist) in one grid ----
// scores[k,l]*sqrt(D) = r_k^T B r_l + (l-const terms, cancel in softmax) + q . r_l
__global__ __launch_bounds__(256) void k_hist_pre(
    const float* __restrict__ vp, int* __restrict__ cell_cnt, int M, int nHist,
    const float* __restrict__ fc_w, const float* __restrict__ fc_b,
    const float* __restrict__ wq_w, const float* __restrict__ wq_b,
    const float* __restrict__ wk_w, const float* __restrict__ wk_b,
    float* __restrict__ ws)
{
    const int tid = threadIdx.x;
    if ((int)blockIdx.x < nHist) {
        int i = blockIdx.x * 256 + tid;
        if (i < M) {
            int cx = cell_coord(vp[i * 3 + 0]);
            int cy = cell_coord(vp[i * 3 + 1]);
            int cz = cell_coord(vp[i * 3 + 2]);
            atomicAdd(&cell_cnt[(cx * G + cy) * G + cz], 1);
        }
        return;
    }
    // ---- precompute block ----
    __shared__ float Fs[768];
    __shared__ float fb[128];
    __shared__ float Gq[128][6];
    __shared__ float Gk[128][6];
    __shared__ float hq[128];

    for (int e = tid; e < 768; e += 256) Fs[e] = fc_w[e];
    if (tid < 128) fb[tid] = fc_b[tid];
    __syncthreads();

    const float4* wq4 = (const float4*)wq_w;
    const float4* wk4 = (const float4*)wk_w;
    for (int e = tid; e < 768; e += 256) {
        int r = e / 6, c = e % 6;
        float aq = 0.f, ak = 0.f;
        for (int k = 0; k < 32; ++k) {
            float4 a = wq4[r * 32 + k];
            float4 b = wk4[r * 32 + k];
            aq += a.x * Fs[(4 * k + 0) * 6 + c];
            aq += a.y * Fs[(4 * k + 1) * 6 + c];
            aq += a.z * Fs[(4 * k + 2) * 6 + c];
            aq += a.w * Fs[(4 * k + 3) * 6 + c];
            ak += b.x * Fs[(4 * k + 0) * 6 + c];
            ak += b.y * Fs[(4 * k + 1) * 6 + c];
            ak += b.z * Fs[(4 * k + 2) * 6 + c];
            ak += b.w * Fs[(4 * k + 3) * 6 + c];
        }
        Gq[r][c] = aq;
        Gk[r][c] = ak;
    }
    if (tid < 128) {
        float a = wq_b[tid];
        for (int k = 0; k < 32; ++k) {
            float4 v = wq4[tid * 32 + k];
            a += v.x * fb[4 * k + 0];
            a += v.y * fb[4 * k + 1];
            a += v.z * fb[4 * k + 2];
            a += v.w * fb[4 * k + 3];
        }
        hq[tid] = a;
    }
    __syncthreads();

    const float inv_s = 0.0883883476483184f; // 1/sqrt(128)
    if (tid < 36) {
        int a = tid / 6, b = tid % 6;
        float s = 0.f;
        for (int i = 0; i < 128; ++i) s += Gq[i][a] * Gk[i][b];
        ws[tid] = s * inv_s;
    }
    if (tid >= 64 && tid < 70) {
        int b = tid - 64;
        float s = 0.f;
        for (int i = 0; i < 128; ++i) s += Gk[i][b] * hq[i];
        ws[36 + b] = s * inv_s;
    }
}

__global__ __launch_bounds__(1024) void k_scan(
    const int* __restrict__ cell_cnt, int* __restrict__ cell_end)
{
    __shared__ int part[1024];
    const int tid = threadIdx.x;
    const int base = tid * (NCELL / 1024);
    int s = 0;
    for (int k = 0; k < NCELL / 1024; ++k) s += cell_cnt[base + k];
    part[tid] = s;
    __syncthreads();
    for (int off = 1; off < 1024; off <<= 1) {
        int v = (tid >= off) ? part[tid - off] : 0;
        __syncthreads();
        part[tid] += v;
        __syncthreads();
    }
    int run = part[tid] - s;
    for (int k = 0; k < NCELL / 1024; ++k) {
        cell_end[base + k] = run;
        run += cell_cnt[base + k];
    }
}

// after this, cell_end[c] = end; range = [end-cnt, end).
__global__ __launch_bounds__(256) void k_scatter(
    const float* __restrict__ vp, int* __restrict__ cell_end,
    float4* __restrict__ sp4, int* __restrict__ sidx, int M)
{
    int i = blockIdx.x * 256 + threadIdx.x;
    if (i < M) {
        float x = vp[i * 3 + 0], y = vp[i * 3 + 1], z = vp[i * 3 + 2];
        int c = (cell_coord(x) * G + cell_coord(y)) * G + cell_coord(z);
        int p = atomicAdd(&cell_end[c], 1);
        sp4[p] = make_float4(x, y, z, 0.0f);
        sidx[p] = i;
    }
}

// ---------------- main: 4 waves/block, one point per wave, round-5 per-wave logic ----------------
__global__ __launch_bounds__(256) void k_main(
    const float* __restrict__ xw, const float* __restrict__ vp,
    const float* __restrict__ vn, const float* __restrict__ vv,
    const float* __restrict__ ws,
    const int* __restrict__ cc, const int* __restrict__ ce,
    const float4* __restrict__ sp4, const int* __restrict__ sidx,
    float* __restrict__ out, int M, int N)
{
    const int tid  = threadIdx.x;
    const int lane = tid & 63;
    const int w    = tid >> 6;
    const int n    = blockIdx.x * NWAVE + w;
    const bool valid = (n < N);

    __shared__ ull   s_key[NWAVE][CAP];
    __shared__ float s_t[NWAVE][KSEL][6];
    __shared__ float s_vn[NWAVE][KSEL][3];
    __shared__ float s_e[NWAVE][KSEL];
    __shared__ float s_v[NWAVE][KSEL];
    __shared__ float s_o[NWAVE][KSEL];
    __shared__ int   s_sel[NWAVE][KSEL];
    __shared__ float s_xn[NWAVE][3];
    __shared__ int   s_cnt[NWAVE];
    __shared__ int   s_done[NWAVE];

    const float x0 = valid ? xw[n * 3 + 0] : 0.f;
    const float x1 = valid ? xw[n * 3 + 1] : 0.f;
    const float x2 = valid ? xw[n * 3 + 2] : 0.f;

    const int cx = cell_coord(x0);
    const int cy = cell_coord(x1);
    const int cz = cell_coord(x2);

    auto midf = [](float a, float b) -> float {
        unsigned ua = __float_as_uint(a), ub = __float_as_uint(b);
        return __uint_as_float((ua + ub) >> 1);
    };

    // damped fixed-point initial radius (starting guess only; search below is exact)
    const float c0 = 0.063493636f * (float)M * 4.18879020f;
    float R = sqrtf(x0 * x0 + x1 * x1 + x2 * x2);
    float r = cbrtf(30.0f / (c0 * __expf(-0.5f * R * R)));
#pragma unroll
    for (int it = 0; it < 4; ++it) {
        float d  = fmaxf(R - r, 0.0f);
        float rn = cbrtf(30.0f / (c0 * __expf(-0.5f * d * d)));
        r = sqrtf(r * rn);
    }
    float T = 1.2f * r * r;

    float Tlo = 0.f, Thi = 0.f;
    bool  haveHi = false, last = false;
    bool  mydone = !valid;
    int   nc = 0;

    for (int attempt = 0; attempt < 24; ++attempt) {
        if (lane == 0) s_cnt[w] = 0;
        __syncthreads();

        if (!mydone) {
            float Tm = T * 1.000002f;
            float sq = sqrtf(T);
            int smax = (int)(sq * INVH) + 2;
            if (smax > G - 1) smax = G - 1;
            int ax0 = max(cx - smax, 0), ax1 = min(cx + smax, G - 1);
            int ay0 = max(cy - smax, 0), ay1 = min(cy + smax, G - 1);
            int az0 = max(cz - smax, 0), az1 = min(cz + smax, G - 1);
            int nx = ax1 - ax0 + 1, nyv = ay1 - ay0 + 1, nz = az1 - az0 + 1;
            int tot = nx * nyv * nz;

            for (int ci = lane; ci < tot; ci += 64) {
                int iz = ci % nz;
                int t2 = ci / nz;
                int iy = t2 % nyv;
                int ix = t2 / nyv;
                ix += ax0; iy += ay0; iz += az0;
                float gx = gap1(x0, ix), gy = gap1(x1, iy), gz = gap1(x2, iz);
                float mind2 = gx * gx + gy * gy + gz * gz;
                if (mind2 <= Tm) {
                    int c = (ix * G + iy) * G + iz;
                    int e   = ce[c];
                    int cnt = cc[c];
                    for (int p = e - cnt; p < e; ++p) {
                        float4 q = sp4[p];
                        float dx = __fsub_rn(x0, q.x);
                        float dy = __fsub_rn(x1, q.y);
                        float dz = __fsub_rn(x2, q.z);
                        float d2 = __fadd_rn(__fadd_rn(__fmul_rn(dx, dx), __fmul_rn(dy, dy)),
                                             __fmul_rn(dz, dz));
                        if (d2 < T) {
                            int pos = atomicAdd(&s_cnt[w], 1);
                            if (pos < CAP) {
                                s_key[w][pos] = ((ull)__float_as_uint(d2) << 32) |
                                                (unsigned)sidx[p];
                            }
                        }
                    }
                }
            }
        }
        __syncthreads();

        if (!mydone) {
            nc = s_cnt[w];
            if (last || (nc >= KSEL && nc <= CAP)) {
                mydone = true;
            } else {
                if (nc < KSEL) { Tlo = T; T = haveHi ? midf(Tlo, Thi) : T * 2.5f; }
                else           { Thi = T; haveHi = true; T = midf(Tlo, Thi); }
                if (haveHi && (__float_as_uint(Thi) - __float_as_uint(Tlo) <= 1u)) {
                    T = Thi;       // final guaranteed-superset pass
                    last = true;
                }
            }
        }
        if (lane == 0) s_done[w] = mydone ? 1 : 0;
        __syncthreads();
        if (s_done[0] && s_done[1] && s_done[2] && s_done[3]) break;
    }
    if (nc > CAP) nc = CAP;

    if (lane < KSEL) s_sel[w][lane] = 0; // safety init
    __syncthreads();

    // exact top-30 by rank (distinct keys; idx tiebreak = lax.top_k)
    for (int i0 = lane; i0 < nc; i0 += 64) {
        ull me = s_key[w][i0];
        int rank = 0;
        for (int i = 0; i < nc; ++i) rank += (s_key[w][i] < me) ? 1 : 0;
        if (rank < KSEL) s_sel[w][rank] = (int)(me & 0xffffffffull);
    }
    __syncthreads();

    // ---- gather features ----
    float r0 = 0.f, r1 = 0.f, r2 = 0.f;
    if (lane < KSEL) {
        int ix = s_sel[w][lane];
        r0 = __fsub_rn(x0, vp[ix * 3 + 0]);
        r1 = __fsub_rn(x1, vp[ix * 3 + 1]);
        r2 = __fsub_rn(x2, vp[ix * 3 + 2]);
        s_vn[w][lane][0] = vn[ix * 3 + 0];
        s_vn[w][lane][1] = vn[ix * 3 + 1];
        s_vn[w][lane][2] = vn[ix * 3 + 2];
        s_v[w][lane]     = vv[ix];
    }
    __syncthreads();
    if (lane == 0) {
        float a0 = 0.f, a1 = 0.f, a2 = 0.f;
        for (int k = 0; k < KNRM; ++k) {
            a0 += s_vn[w][k][0]; a1 += s_vn[w][k][1]; a2 += s_vn[w][k][2];
        }
        s_xn[w][0] = a0 * 0.125f; s_xn[w][1] = a1 * 0.125f; s_xn[w][2] = a2 * 0.125f;
    }
    __syncthreads();

    float r3 = 0.f, r4 = 0.f, r5 = 0.f;
    if (lane < KSEL) {
        r3 = __fsub_rn(s_xn[w][0], s_vn[w][lane][0]);
        r4 = __fsub_rn(s_xn[w][1], s_vn[w][lane][1]);
        r5 = __fsub_rn(s_xn[w][2], s_vn[w][lane][2]);
        float rr[6] = {r0, r1, r2, r3, r4, r5};
        float e = 0.f;
#pragma unroll
        for (int i = 0; i < 6; ++i) e += ws[36 + i] * rr[i];
        s_e[w][lane] = e;
#pragma unroll
        for (int j = 0; j < 6; ++j) {
            float t = 0.f;
#pragma unroll
            for (int i = 0; i < 6; ++i) t += ws[j * 6 + i] * rr[i];
            s_t[w][lane][j] = t;
        }
    }
    __syncthreads();

    if (lane < KSEL) {
        float sc[KSEL];
        float mx = -1e30f;
#pragma unroll
        for (int l = 0; l < KSEL; ++l) {
            float s = s_e[w][l];
            s += r0 * s_t[w][l][0];
            s += r1 * s_t[w][l][1];
            s += r2 * s_t[w][l][2];
            s += r3 * s_t[w][l][3];
            s += r4 * s_t[w][l][4];
            s += r5 * s_t[w][l][5];
            sc[l] = s;
            mx = fmaxf(mx, s);
        }
        float den = 0.f, num = 0.f;
#pragma unroll
        for (int l = 0; l < KSEL; ++l) {
            float wgt = __expf(sc[l] - mx);
            den += wgt;
            num += wgt * s_v[w][l];
        }
        s_o[w][lane] = num / den;
    }
    __syncthreads();

    if (lane == 0 && valid) {
        float a = 0.f;
        for (int k = 0; k < KSEL; ++k) a += s_o[w][k];
        out[n] = a * (1.0f / 30.0f);
    }
}

extern "C" void kernel_launch(void* const* d_in, const int* in_sizes, int n_in,
                              void* d_out, int out_size, void* d_ws, size_t ws_size,
                              hipStream_t stream)
{
    const float* xw   = (const float*)d_in[0];
    const float* vp   = (const float*)d_in[1];
    const float* vn   = (const float*)d_in[2];
    const float* vv   = (const float*)d_in[3];
    const float* fc_w = (const float*)d_in[4];
    const float* fc_b = (const float*)d_in[5];
    const float* wq_w = (const float*)d_in[6];
    const float* wq_b = (const float*)d_in[7];
    const float* wk_w = (const float*)d_in[8];
    const float* wk_b = (const float*)d_in[9];

    int N = in_sizes[0] / 3;
    int M = in_sizes[1] / 3;

    float*  ws_f = (float*)d_ws;
    int*    cc   = (int*)(ws_f + 64);
    int*    ce   = cc + NCELL;
    float4* sp4  = (float4*)(ce + NCELL);    // byte offset 262400, 16B-aligned
    int*    sidx = (int*)(sp4 + M);

    hipMemsetAsync(cc, 0, NCELL * sizeof(int), stream);

    int nHist = (M + 255) / 256;
    k_hist_pre<<<nHist + 1, 256, 0, stream>>>(vp, cc, M, nHist,
                                              fc_w, fc_b, wq_w, wq_b, wk_w, wk_b, ws_f);
    k_scan<<<1, 1024, 0, stream>>>(cc, ce);
    k_scatter<<<nHist, 256, 0, stream>>>(vp, ce, sp4, sidx, M);
    k_main<<<(N + NWAVE - 1) / NWAVE, 256, 0, stream>>>(
        xw, vp, vn, vv, ws_f, cc, ce, sp4, sidx, (float*)d_out, M, N);
}